// Round 6
// baseline (97.604 us; speedup 1.0000x reference)
//
#include <hip/hip_runtime.h>

#define B_   64
#define T_   2000
#define RNN_ 1024
#define EMB_ 512
#define ATT_ 128
#define CH_  8
#define K_   21
#define PL_  11
#define GSZ  168   // CH_*K_
#define ECHK 128   // energy chunk (16 per batch)
#define NEC  16
#define NCS  16    // ctx col-stripe blocks per batch (32 cols each)
#define CPS  32    // cols per stripe
#define WSEG 125   // w rows written back per ctx block

typedef float vf4 __attribute__((ext_vector_type(4)));

__device__ __forceinline__ float fast_tanh(float x) {
    float ax = fabsf(x);
    float e  = __expf(2.0f * ax);
    float t  = 1.0f - 2.0f / (e + 1.0f);
    return copysignf(t, x);
}

// ---- kernel 1: G = tanh(q @ W_w^T + W_b) @ V_w^T  -> [B,168] ----
__global__ __launch_bounds__(256) void k_gen_dyn(
    const float* __restrict__ q, const float* __restrict__ Ww,
    const float* __restrict__ Wb, const float* __restrict__ Vw,
    float* __restrict__ G)
{
    __shared__ float sq[RNN_];
    __shared__ float part[256];
    __shared__ float sh[ATT_];
    const int b = blockIdx.x, tid = threadIdx.x;
    for (int i = tid; i < RNN_; i += 256) sq[i] = q[b * RNN_ + i];
    __syncthreads();
    {
        const int row = tid & 127, half = tid >> 7;        // 2-way K split
        const float4* wr = reinterpret_cast<const float4*>(Ww + row * RNN_ + half * (RNN_ / 2));
        const float4* qr = reinterpret_cast<const float4*>(sq + half * (RNN_ / 2));
        float acc = 0.f;
        #pragma unroll 8
        for (int i = 0; i < RNN_ / 8; ++i) {
            float4 w4 = wr[i], q4 = qr[i];
            acc += w4.x * q4.x + w4.y * q4.y + w4.z * q4.z + w4.w * q4.w;
        }
        part[tid] = acc;
    }
    __syncthreads();
    if (tid < ATT_) sh[tid] = fast_tanh(part[tid] + part[tid + 128] + Wb[tid]);
    __syncthreads();
    for (int o = tid; o < GSZ; o += 256) {
        const float4* vr = reinterpret_cast<const float4*>(Vw + o * ATT_);
        const float4* hr = reinterpret_cast<const float4*>(sh);
        float acc = 0.f;
        #pragma unroll 8
        for (int i = 0; i < ATT_ / 4; ++i) {
            float4 v4 = vr[i], h4 = hr[i];
            acc += v4.x * h4.x + v4.y * h4.y + v4.z * h4.z + v4.w * h4.w;
        }
        G[b * GSZ + o] = acc;
    }
}

// ---- kernel 2: energy (2-way d-split) + chunk max/sum -> pws = exp(e - m_c) ----
__global__ __launch_bounds__(256) void k_energy(
    const float* __restrict__ a,  const float* __restrict__ G,
    const float* __restrict__ Fw, const float* __restrict__ Uw,
    const float* __restrict__ Tw, const float* __restrict__ Tb,
    const float* __restrict__ vw, const float* __restrict__ P,
    const unsigned char* __restrict__ mask,
    float* __restrict__ pws, float* __restrict__ mred, float* __restrict__ sred)
{
    __shared__ float sA[ECHK + K_ - 1];  // 148 window
    __shared__ float sFG[K_ * 16];       // [k][16]: c<8 = F_w[c][k], c>=8 = G[b][(c-8)*21+k]
    __shared__ float sUT[ATT_ * 16];     // [d][16]: c<8 = U_w[d][c], c>=8 = T_w[d][c-8]
    __shared__ float sTb[ATT_], sV[ATT_], sPr[PL_];
    __shared__ float sQ[2 * ECHK];       // [h][t] half-partials of MLP output
    __shared__ float red[4];
    const int b = blockIdx.x, chunk = blockIdx.y, tid = threadIdx.x;
    const int t0 = chunk * ECHK;
    const int base = t0 - (K_ - 1) / 2;  // t0 - 10
    const int tloc = tid & (ECHK - 1);
    const int h = tid >> 7;

    for (int j = tid; j < ECHK + K_ - 1; j += 256) {
        int idx = base + j;
        sA[j] = (idx >= 0 && idx < T_) ? a[b * T_ + idx] : 0.f;
    }
    for (int j = tid; j < 2 * GSZ; j += 256) {
        if (j < GSZ) sFG[(j % K_) * 16 + (j / K_)] = Fw[j];
        else { int jj = j - GSZ; sFG[(jj % K_) * 16 + 8 + (jj / K_)] = G[b * GSZ + jj]; }
    }
    for (int j = tid; j < ATT_ * CH_; j += 256) {
        int d = j >> 3, c = j & 7;
        sUT[d * 16 + c]     = Uw[j];
        sUT[d * 16 + 8 + c] = Tw[j];
    }
    if (tid < ATT_) { sTb[tid] = Tb[tid]; sV[tid] = vw[tid]; }
    if (tid < PL_)  sPr[tid] = P[tid];
    __syncthreads();

    // conv features (redundant across halves, cheap)
    float fg[16];
    #pragma unroll
    for (int i = 0; i < 16; ++i) fg[i] = 0.f;
    #pragma unroll
    for (int k = 0; k < K_; ++k) {
        float av = sA[tloc + k];
        const float4* fp = reinterpret_cast<const float4*>(&sFG[k * 16]);
        float4 x0 = fp[0], x1 = fp[1], x2 = fp[2], x3 = fp[3];
        fg[0]  += x0.x * av; fg[1]  += x0.y * av; fg[2]  += x0.z * av; fg[3]  += x0.w * av;
        fg[4]  += x1.x * av; fg[5]  += x1.y * av; fg[6]  += x1.z * av; fg[7]  += x1.w * av;
        fg[8]  += x2.x * av; fg[9]  += x2.y * av; fg[10] += x2.z * av; fg[11] += x2.w * av;
        fg[12] += x3.x * av; fg[13] += x3.y * av; fg[14] += x3.z * av; fg[15] += x3.w * av;
    }

    // MLP: this thread handles dims [h*64, h*64+64)
    float accQ = 0.f;
    const int d0 = h * 64;
    #pragma unroll 4
    for (int dd = 0; dd < 64; ++dd) {
        const int d = d0 + dd;
        const float4* up = reinterpret_cast<const float4*>(&sUT[d * 16]);
        float4 u0 = up[0], u1 = up[1], u2 = up[2], u3 = up[3];
        float s0 = u0.x * fg[0]  + u0.y * fg[1]  + u0.z * fg[2]  + u0.w * fg[3];
        float s1 = u1.x * fg[4]  + u1.y * fg[5]  + u1.z * fg[6]  + u1.w * fg[7];
        float s2 = u2.x * fg[8]  + u2.y * fg[9]  + u2.z * fg[10] + u2.w * fg[11];
        float s3 = u3.x * fg[12] + u3.y * fg[13] + u3.z * fg[14] + u3.w * fg[15];
        float s = (sTb[d] + s0) + (s1 + s2) + s3;
        accQ += sV[d] * fast_tanh(s);
    }
    sQ[h * ECHK + tloc] = accQ;
    __syncthreads();

    // energies for tid < 128; others carry -inf through the block reduction
    float e = -1e30f;
    const int t = t0 + tid;
    if (tid < ECHK) {
        const bool valid = (t < T_) && !mask[b * T_ + min(t, T_ - 1)];
        if (valid) {
            float pp = 0.f;
            #pragma unroll
            for (int k = 0; k < PL_; ++k) pp += sPr[k] * sA[tid + k];
            e = sQ[tid] + sQ[ECHK + tid] + __logf(fmaxf(pp, 1e-6f));
        }
    }
    float m = e;
    #pragma unroll
    for (int off = 32; off > 0; off >>= 1) m = fmaxf(m, __shfl_xor(m, off));
    if ((tid & 63) == 0) red[tid >> 6] = m;
    __syncthreads();
    const float Mc = fmaxf(fmaxf(red[0], red[1]), fmaxf(red[2], red[3]));
    __syncthreads();
    float pv = (e > -1e29f) ? __expf(e - Mc) : 0.f;
    if (tid < ECHK && t < T_) pws[b * T_ + t] = pv;
    float ssum = pv;
    #pragma unroll
    for (int off = 32; off > 0; off >>= 1) ssum += __shfl_xor(ssum, off);
    if ((tid & 63) == 0) red[tid >> 6] = ssum;
    __syncthreads();
    if (tid == 0) {
        mred[b * NEC + chunk] = Mc;
        sred[b * NEC + chunk] = red[0] + red[1] + red[2] + red[3];
    }
}

// ---- kernel 3: col-stripe context: normalize w in LDS, stream rows, direct store ----
__global__ __launch_bounds__(256) void k_ctx(
    const float* __restrict__ mred, const float* __restrict__ sred,
    const float* __restrict__ pws, const float* __restrict__ mem,
    float* __restrict__ wout, float* __restrict__ out)
{
    __shared__ float sAl[NEC];
    __shared__ float sw_[T_];          // 8 KB normalized weights
    __shared__ vf4 sPart[32][8];       // 4 KB partials
    const int b = blockIdx.x, cs = blockIdx.y, tid = threadIdx.x;

    if (tid < NEC) {
        float M = -1e30f;
        #pragma unroll
        for (int i = 0; i < NEC; ++i) M = fmaxf(M, mred[b * NEC + i]);
        float S = 0.f;
        #pragma unroll
        for (int i = 0; i < NEC; ++i) S += sred[b * NEC + i] * __expf(mred[b * NEC + i] - M);
        sAl[tid] = __expf(mred[b * NEC + tid] - M) / S;
    }
    __syncthreads();
    for (int j = tid; j < T_; j += 256) sw_[j] = pws[b * T_ + j] * sAl[j >> 7];
    __syncthreads();
    // distributed write-back of normalized weights (disjoint 125-row segments)
    if (tid < WSEG) {
        const int t = cs * WSEG + tid;
        wout[b * T_ + t] = sw_[t];
    }

    // stream this block's 32-column stripe over all 2000 rows
    const int lane = tid & 7, rgrp = tid >> 3;   // 8 col-lanes, 32 row-groups
    const float* basep = mem + (size_t)b * T_ * EMB_ + cs * CPS + lane * 4;
    vf4 acc = {0.f, 0.f, 0.f, 0.f};
    #pragma unroll 8
    for (int i = 0; i < 62; ++i) {
        const int t = rgrp + i * 32;
        vf4 mv = *reinterpret_cast<const vf4*>(basep + (size_t)t * EMB_);
        acc += sw_[t] * mv;
    }
    if (rgrp < 16) {                              // tail rows 1984..1999
        const int t = rgrp + 1984;
        vf4 mv = *reinterpret_cast<const vf4*>(basep + (size_t)t * EMB_);
        acc += sw_[t] * mv;
    }
    sPart[rgrp][lane] = acc;
    __syncthreads();
    if (tid < 64) {
        const int l = tid & 7, qg = tid >> 3;
        vf4 r = sPart[qg][l] + sPart[qg + 8][l] + sPart[qg + 16][l] + sPart[qg + 24][l];
        sPart[qg][l] = r;
    }
    __syncthreads();
    if (tid < 8) {
        vf4 r = sPart[0][tid] + sPart[1][tid] + sPart[2][tid] + sPart[3][tid]
              + sPart[4][tid] + sPart[5][tid] + sPart[6][tid] + sPart[7][tid];
        *reinterpret_cast<vf4*>(out + b * EMB_ + cs * CPS + tid * 4) = r;
    }
}

extern "C" void kernel_launch(void* const* d_in, const int* in_sizes, int n_in,
                              void* d_out, int out_size, void* d_ws, size_t ws_size,
                              hipStream_t stream)
{
    const float* q    = (const float*)d_in[0];
    const float* mem  = (const float*)d_in[1];
    const float* a    = (const float*)d_in[2];
    const unsigned char* mask = (const unsigned char*)d_in[3];
    const float* Ww = (const float*)d_in[4];
    const float* Wb = (const float*)d_in[5];
    const float* Vw = (const float*)d_in[6];
    const float* Fw = (const float*)d_in[7];
    const float* Uw = (const float*)d_in[8];
    const float* Tw = (const float*)d_in[9];
    const float* Tb = (const float*)d_in[10];
    const float* vw = (const float*)d_in[11];
    const float* P  = (const float*)d_in[12];

    float* out_ctx = (float*)d_out;           // [64*512]
    float* out_w   = out_ctx + B_ * EMB_;     // [64*2000]

    float* G    = (float*)d_ws;               // [64*168]
    float* mred = G + B_ * GSZ;               // [64*16]
    float* sred = mred + B_ * NEC;            // [64*16]
    float* pws  = sred + B_ * NEC;            // [64*2000] unnormalized p

    k_gen_dyn<<<B_, 256, 0, stream>>>(q, Ww, Wb, Vw, G);
    k_energy<<<dim3(B_, NEC), 256, 0, stream>>>(a, G, Fw, Uw, Tw, Tb, vw, P,
                                                mask, pws, mred, sred);
    k_ctx<<<dim3(B_, NCS), 256, 0, stream>>>(mred, sred, pws, mem, out_w, out_ctx);
}